// Round 14
// baseline (134.033 us; speedup 1.0000x reference)
//
#include <hip/hip_runtime.h>
#include <math.h>

#define B_SZ 2048
#define R_SZ 64
#define QT 8                    // q rows per kde block
#define KDE_BLOCKS (B_SZ / QT)  // 256 blocks x 16 waves

#define B_POW_NEG02 0.217637640824031f   // 2048^-0.2 = 2^-2.2
#define SQRT_2PI 2.5066282746310002f
#define LOG2E 1.44269504088896340736f

typedef __attribute__((ext_vector_type(2))) float f32x2;  // -> v_pk_* f32 ops

// ---------------------------------------------------------------------------
// Polynomial exp2 on the FMA pipe (no v_exp_f32). y <= 0.
// exp2(y) = 2^round(y) * p(f),  f = y - round(y) in [-0.5, 0.5].
// Round via magic-constant add; 2^n scale via bit-add of (n << 23)
// (as_int(y+MAGIC) << 23 == n << 23 mod 2^32). Taylor deg-5: rel err <3e-6.
// ---------------------------------------------------------------------------
#define MAGICF 12582912.0f      // 0x1.8p23
#define EC1 0.69314718056f
#define EC2 0.24022650696f
#define EC3 0.05550410866f
#define EC4 0.00961812911f
#define EC5 0.00133335581f

__device__ __forceinline__ f32x2 exp2_poly2(f32x2 y) {
    f32x2 lo = { -126.f, -126.f };
    f32x2 mg = { MAGICF, MAGICF };
    y = __builtin_elementwise_max(y, lo);          // v_pk_max_f32
    f32x2 t = y + mg;                              // round(y) in mantissa
    f32x2 f = y - (t - mg);                        // f in [-0.5, 0.5]
    f32x2 p = { EC5, EC5 };
    f32x2 c4 = { EC4, EC4 }, c3 = { EC3, EC3 }, c2 = { EC2, EC2 };
    f32x2 c1 = { EC1, EC1 }, c0 = { 1.f, 1.f };
    p = p * f + c4;                                // v_pk_fma_f32 chain
    p = p * f + c3;
    p = p * f + c2;
    p = p * f + c1;
    p = p * f + c0;
    int ex = __float_as_int(t.x) << 23;            // n << 23
    int ey = __float_as_int(t.y) << 23;
    f32x2 r;
    r.x = __int_as_float(__float_as_int(p.x) + ex);
    r.y = __int_as_float(__float_as_int(p.y) + ey);
    return r;
}

// ---------------------------------------------------------------------------
// ws layout (floats):
//   [0:64)    lscale       = 1/(B*h*sqrt(2pi))
//   [64:128)  cov_partial  (one per receptor row)
//   [160]     ent_acc      (own 128B line)
//   [192]     done_cnt     (int, own line)
//   [256:256+131072)  U = kscale[r]*A  (prescaled input, 512 KB)
// ---------------------------------------------------------------------------

// Kernel 1: fused stats + Gram row + cov row + U prescale + flag init.
// (byte-identical to R9 — verified)
__global__ __launch_bounds__(1024) void cov_stats_kernel(const float* __restrict__ A,
                                                         float* __restrict__ U,
                                                         float* __restrict__ lscale,
                                                         float* __restrict__ cov_partial,
                                                         float* __restrict__ ent_acc,
                                                         int* __restrict__ done_cnt) {
    int i = blockIdx.x;
    int tid = threadIdx.x;
    int j = tid & 63, bg = tid >> 6;          // 16 b-groups

    float g = 0.f, sj = 0.f, s2j = 0.f;
#pragma unroll 4
    for (int b = bg; b < B_SZ; b += 16) {
        float ai = A[b * R_SZ + i];           // wave-uniform broadcast
        float aj = A[b * R_SZ + j];           // coalesced
        g = fmaf(ai, aj, g);
        sj += aj;
        s2j = fmaf(aj, aj, s2j);
    }

    __shared__ float gred[16][64], sred[16][64], s2red[16][64];
    __shared__ float gfin[64], sfin[64], hs[64];
    gred[bg][j] = g; sred[bg][j] = sj; s2red[bg][j] = s2j;
    __syncthreads();
    if (tid < 64) {
        float G = 0.f, S = 0.f, S2 = 0.f;
#pragma unroll
        for (int t = 0; t < 16; ++t) { G += gred[t][j]; S += sred[t][j]; S2 += s2red[t][j]; }
        gfin[j] = G;
        sfin[j] = S;
        float m = S * (1.f / (float)B_SZ);
        float var = (S2 - S * m) * (1.f / (float)(B_SZ - 1));   // ddof=1
        var = fmaxf(var, 0.f);
        float h = fmaxf(1.06f * sqrtf(var) * B_POW_NEG02, 1e-4f);
        hs[j] = sqrtf(0.5f * LOG2E) / h;      // exp2(-(k*d)^2) = exp(-0.5(d/h)^2)
        if (i == 0) lscale[j] = 1.0f / ((float)B_SZ * h * SQRT_2PI);
    }
    __syncthreads();
    if (tid < 64) {                            // covariance row i
        float m_j = sfin[j] * (1.f / (float)B_SZ);
        float m_i = sfin[i] * (1.f / (float)B_SZ);
        float cov = (gfin[j] - (float)B_SZ * m_i * m_j) * (1.f / (float)(B_SZ - 1));
        float v = (j == i) ? 0.f : cov * cov;
        for (int off = 32; off > 0; off >>= 1) v += __shfl_down(v, off, 64);
        if (j == 0) cov_partial[i] = v;
    }
    if (i == 0 && tid == 64) { *ent_acc = 0.f; *done_cnt = 0; }

    // prescale U rows [i*32, i*32+32): 2048 elems, 2 per thread (coalesced)
    int base = i * (32 * R_SZ);
    float k0 = hs[tid & 63];
    U[base + tid]        = A[base + tid]        * k0;
    U[base + 1024 + tid] = A[base + 1024 + tid] * k0;
}

// ---------------------------------------------------------------------------
// Kernel 2: pairwise KDE — R9's exact structure, exp via FMA-pipe polynomial
// (ONLY change vs R9: KDE_BODY uses exp2_poly2 instead of v_exp_f32).
// ---------------------------------------------------------------------------
__global__ __launch_bounds__(1024) void kde_kernel(const float* __restrict__ U,
                                                   const float* __restrict__ lscale,
                                                   const float* __restrict__ cov_partial,
                                                   float* __restrict__ ent_acc,
                                                   int* __restrict__ done_cnt,
                                                   float* __restrict__ out) {
    int tid = threadIdx.x;
    int r = tid & 63, sg = tid >> 6;
    int q0 = blockIdx.x * QT;

    f32x2 uq01 = { U[(q0 + 0) * R_SZ + r], U[(q0 + 1) * R_SZ + r] };
    f32x2 uq23 = { U[(q0 + 2) * R_SZ + r], U[(q0 + 3) * R_SZ + r] };
    f32x2 uq45 = { U[(q0 + 4) * R_SZ + r], U[(q0 + 5) * R_SZ + r] };
    f32x2 uq67 = { U[(q0 + 6) * R_SZ + r], U[(q0 + 7) * R_SZ + r] };
    f32x2 c01 = { 0.f, 0.f }, c23 = { 0.f, 0.f };
    f32x2 c45 = { 0.f, 0.f }, c67 = { 0.f, 0.f };

#define KDE_BODY(usv)                                                          \
    {                                                                          \
        f32x2 uss = { (usv), (usv) };                                          \
        f32x2 d01 = uq01 - uss, d23 = uq23 - uss;                              \
        f32x2 d45 = uq45 - uss, d67 = uq67 - uss;                              \
        f32x2 n01 = -d01 * d01, n23 = -d23 * d23;                              \
        f32x2 n45 = -d45 * d45, n67 = -d67 * d67;                              \
        c01 += exp2_poly2(n01); c23 += exp2_poly2(n23);                        \
        c45 += exp2_poly2(n45); c67 += exp2_poly2(n67);                        \
    }

    // wave sg consumes s = sg + 16k, k = 0..127; element stride 16*64 = 1024
    const float* Up = U + sg * R_SZ + r;
    float p[8];
#pragma unroll
    for (int jj = 0; jj < 8; ++jj) p[jj] = Up[jj * 1024];   // 8 in flight

    int li = 8 * 1024;
#pragma unroll 1
    for (int k = 0; k < 15; ++k) {                     // 15 x 8 = 120 consumed
#pragma unroll
        for (int jj = 0; jj < 8; ++jj) {
            float us = p[jj];
            p[jj] = Up[li + jj * 1024];                // prefetch k+8 group
            KDE_BODY(us);
        }
        li += 8 * 1024;
    }
#pragma unroll
    for (int jj = 0; jj < 8; ++jj) KDE_BODY(p[jj]);    // drain last 8

#undef KDE_BODY

    // cross-wave reduction of the 8 query-row densities (32 KB LDS)
    __shared__ float red[16][QT][64];
    red[sg][0][r] = c01.x; red[sg][1][r] = c01.y;
    red[sg][2][r] = c23.x; red[sg][3][r] = c23.y;
    red[sg][4][r] = c45.x; red[sg][5][r] = c45.y;
    red[sg][6][r] = c67.x; red[sg][7][r] = c67.y;
    __syncthreads();
    __shared__ float wred[QT];
    if (sg < QT) {                             // wave sg owns query row sg
        float S = 0.f;
#pragma unroll
        for (int t = 0; t < 16; ++t) S += red[t][sg][r];
        float v = __logf(fmaf(S, lscale[r], 1e-8f));
        for (int off = 32; off > 0; off >>= 1) v += __shfl_down(v, off, 64);
        if (r == 0) wred[sg] = v;
    }
    __syncthreads();
    __shared__ int lastflag;
    if (tid == 0) {
        float p2 = 0.f;
#pragma unroll
        for (int t = 0; t < QT; ++t) p2 += wred[t];
        p2 *= (1.0f / ((float)B_SZ * (float)R_SZ));
        atomicAdd(ent_acc, p2);                // once per block
        __threadfence();
        int prev = atomicAdd(done_cnt, 1);
        lastflag = (prev == KDE_BLOCKS - 1);
    }
    __syncthreads();
    if (lastflag && tid < 64) {                // grid-final fold in last block
        __threadfence();
        float v = cov_partial[tid];
        for (int off = 32; off > 0; off >>= 1) v += __shfl_down(v, off, 64);
        if (tid == 0) {
            float ent = __hip_atomic_load(ent_acc, __ATOMIC_ACQUIRE,
                                          __HIP_MEMORY_SCOPE_AGENT);
            out[0] = ent + v;                  // COV_WEIGHT = 1.0
        }
    }
}

extern "C" void kernel_launch(void* const* d_in, const int* in_sizes, int n_in,
                              void* d_out, int out_size, void* d_ws, size_t ws_size,
                              hipStream_t stream) {
    const float* A = (const float*)d_in[0];
    float* out = (float*)d_out;

    float* wsf = (float*)d_ws;
    float* lscale      = wsf;            // 64
    float* cov_partial = wsf + 64;       // 64
    float* ent_acc     = wsf + 160;      // isolated cache line
    int*   done_cnt    = (int*)(wsf + 192);
    float* U           = wsf + 256;      // 2048*64 prescaled input

    cov_stats_kernel<<<R_SZ, 1024, 0, stream>>>(A, U, lscale, cov_partial,
                                                ent_acc, done_cnt);
    kde_kernel<<<KDE_BLOCKS, 1024, 0, stream>>>(U, lscale, cov_partial,
                                                ent_acc, done_cnt, out);
}